// Round 14
// baseline (475.494 us; speedup 1.0000x reference)
//
#include <hip/hip_runtime.h>
#include <cstdint>
#include <cstddef>

typedef _Float16 f16;
typedef _Float16 f16x4 __attribute__((ext_vector_type(4)));
typedef _Float16 f16x8 __attribute__((ext_vector_type(8)));
typedef float f32x4 __attribute__((ext_vector_type(4)));

#define LRELU_SLOPE 0.2f

#define GLL16(g, l)                                                          \
  __builtin_amdgcn_global_load_lds(                                          \
      (const __attribute__((address_space(1))) void*)(g),                    \
      (__attribute__((address_space(3))) void*)(l), 16, 0, 0)

// ---------------- prep: x (f32) -> x_h (f16), padded rows zeroed ----------------
__global__ __launch_bounds__(256) void k_prep_xh(const float* __restrict__ x,
                                                 f16* __restrict__ xh,
                                                 int nvalid, int npad) {
  int total = npad * 192;
  for (int idx = blockIdx.x * blockDim.x + threadIdx.x; idx < total;
       idx += gridDim.x * blockDim.x) {
    int row = idx / 192;
    f16x4 o;
    if (row < nvalid) {
      const float4 v = *(const float4*)(x + (size_t)idx * 4);
      o[0] = (f16)v.x; o[1] = (f16)v.y; o[2] = (f16)v.z; o[3] = (f16)v.w;
    } else {
      o[0] = (f16)0.f; o[1] = (f16)0.f; o[2] = (f16)0.f; o[3] = (f16)0.f;
    }
    *(f16x4*)(xh + (size_t)idx * 4) = o;
  }
}

// ---------------- both W [768][768] f32 -> Wt [n][k] f16, one launch ----------------
__global__ __launch_bounds__(256) void k_transpose_w2(const float* __restrict__ W1,
                                                      const float* __restrict__ W2,
                                                      f16* __restrict__ Wt1,
                                                      f16* __restrict__ Wt2) {
  const float* W = blockIdx.z ? W2 : W1;
  f16* Wt = blockIdx.z ? Wt2 : Wt1;
  __shared__ float tile[32][33];
  int bn = blockIdx.x * 32;
  int bk = blockIdx.y * 32;
  int tx = threadIdx.x & 31, ty = threadIdx.x >> 5;
  #pragma unroll
  for (int r = ty; r < 32; r += 8)
    tile[r][tx] = W[(size_t)(bk + r) * 768 + bn + tx];
  __syncthreads();
  #pragma unroll
  for (int r = ty; r < 32; r += 8)
    Wt[(size_t)(bn + r) * 768 + bk + tx] = (f16)tile[tx][r];
}

// ---------------- CSR build ----------------
__global__ void k_hist(const int* __restrict__ dst, int E, int* __restrict__ counts) {
  for (int e = blockIdx.x * blockDim.x + threadIdx.x; e < E;
       e += gridDim.x * blockDim.x) atomicAdd(&counts[dst[e]], 1);
}

__global__ __launch_bounds__(1024) void k_scan_block(const int* __restrict__ counts,
                                                     int* __restrict__ starts,
                                                     int* __restrict__ cursor, int n) {
  const int t = threadIdx.x;
  const int nthr = 1024;
  const int chunk = (n + nthr - 1) / nthr;
  const int base = t * chunk;
  int tsum = 0;
  for (int i = 0; i < chunk; i++) {
    int idx = base + i;
    if (idx < n) tsum += counts[idx];
  }
  int lane = t & 63, wv = t >> 6;
  int s = tsum;
  #pragma unroll
  for (int off = 1; off < 64; off <<= 1) {
    int tmp = __shfl_up(s, off);
    if (lane >= off) s += tmp;
  }
  __shared__ int wsum[16];
  if (lane == 63) wsum[wv] = s;
  __syncthreads();
  int woff = 0;
  for (int w = 0; w < wv; w++) woff += wsum[w];
  int run = woff + s - tsum;
  for (int i = 0; i < chunk; i++) {
    int idx = base + i;
    if (idx < n) {
      starts[idx] = run;
      cursor[idx] = run;
      run += counts[idx];
    }
  }
  if (t == nthr - 1) starts[n] = run;
}

__global__ void k_fill(const int* __restrict__ src, const int* __restrict__ dst, int E,
                       int* __restrict__ cursor, int* __restrict__ src_sorted) {
  for (int e = blockIdx.x * blockDim.x + threadIdx.x; e < E;
       e += gridDim.x * blockDim.x) {
    int slot = atomicAdd(&cursor[dst[e]], 1);
    src_sorted[slot] = src[e];
  }
}

// ---------------- fp16 MFMA GEMM: B-strip resident in LDS, barrier-free K-loop ---
// Tile 128x64, 4 waves (2M x 2N, wave tile 64x32, acc[4][2]). B strip (64 cols x
// 384 K = 48KB) staged in 2 phases; after each stage: ONE __syncthreads, then 12
// k-steps with NO barriers (B from LDS [kc][col][8] -> 16-lane-contiguous reads,
// conflict-free; A direct-to-register, compiler-pipelined). 3 blocks/CU.
// XCD swizzle m-major over the 12 n-strips: A panel fetched once per XCD.
__global__ __launch_bounds__(256, 3) void k_gemm_f16(const f16* __restrict__ A,
                                                     const f16* __restrict__ Bt,
                                                     f16* __restrict__ C, int Mvalid) {
  __shared__ __align__(16) f16 Bs[48 * 64 * 8];  // [kc][col][8 f16] = 48KB
  const int K = 768;
  const int tid = threadIdx.x;

  const int nwg = gridDim.x;
  const int orig = blockIdx.x;
  const int q = nwg >> 3, r = nwg & 7;
  const int xcd = orig & 7;
  const int wgid = (xcd < r ? xcd * (q + 1) : r * (q + 1) + (xcd - r) * q) + (orig >> 3);
  const int bm = (wgid / 12) * 128;
  const int bn = (wgid - (wgid / 12) * 12) * 64;

  const int lane = tid & 63;
  const int wave = tid >> 6;
  const int wr = (wave >> 1) * 64;   // wave row offset (0/64)
  const int wc = (wave & 1) * 32;    // wave col offset (0/32)
  const int fr = lane & 15;
  const int fq = lane >> 4;

  // B staging: pass p, cell = p*256+tid; col = cell&63, kc = cell>>6.
  // global addr = Bt[(bn+col)*768 + ph*384 + kc*8]; LDS linear (wave-uniform+lane*16).
  size_t goffB[12];
  #pragma unroll
  for (int p = 0; p < 12; p++) {
    const int cell = p * 256 + tid;
    const int col = cell & 63;
    const int kc = cell >> 6;
    goffB[p] = (size_t)(bn + col) * K + kc * 8;
  }

  // A row base pointers (fq's k-offset folded in)
  const f16* arow[4];
  #pragma unroll
  for (int i = 0; i < 4; i++)
    arow[i] = A + (size_t)(bm + wr + i * 16 + fr) * K + fq * 8;

  f32x4 acc[4][2];
  const f32x4 vzero = {0.f, 0.f, 0.f, 0.f};
  #pragma unroll
  for (int i = 0; i < 4; i++)
    #pragma unroll
    for (int j = 0; j < 2; j++) acc[i][j] = vzero;

  #pragma unroll
  for (int ph = 0; ph < 2; ph++) {
    if (ph) __syncthreads();  // all waves done reading Bs before overwrite
    #pragma unroll
    for (int p = 0; p < 12; p++)
      GLL16(Bt + goffB[p] + ph * 384, Bs + (p * 256 + (tid & ~63)) * 8 + (lane)*8);
    __syncthreads();  // drains vmcnt (compiler-inserted) + barrier

    #pragma unroll 2
    for (int t = 0; t < 12; t++) {
      f16x8 af[4], bf[2];
      #pragma unroll
      for (int i = 0; i < 4; i++)
        af[i] = *(const f16x8*)(arow[i] + ph * 384 + t * 32);
      #pragma unroll
      for (int j = 0; j < 2; j++) {
        const int col = wc + j * 16 + fr;
        const int kc = t * 4 + fq;
        bf[j] = *(const f16x8*)(&Bs[(kc * 64 + col) * 8]);
      }
      #pragma unroll
      for (int i = 0; i < 4; i++)
        #pragma unroll
        for (int j = 0; j < 2; j++)
          acc[i][j] = __builtin_amdgcn_mfma_f32_16x16x32_f16(af[i], bf[j], acc[i][j], 0, 0, 0);
    }
  }

  #pragma unroll
  for (int i = 0; i < 4; i++) {
    #pragma unroll
    for (int j = 0; j < 2; j++) {
      const int col = bn + wc + j * 16 + fr;
      #pragma unroll
      for (int rg = 0; rg < 4; rg++) {
        const int row = bm + wr + i * 16 + fq * 4 + rg;
        if (row < Mvalid) C[(size_t)row * 768 + col] = (f16)acc[i][j][rg];
      }
    }
  }
}

// ---------------- attention logits: al[n][h] = sum_c h[n][h*C+c]*a[h][c] ----------
template <int H>
__global__ __launch_bounds__(256) void k_al(const f16* __restrict__ h,
                                            const float* __restrict__ a_src,
                                            const float* __restrict__ a_dst,
                                            float* __restrict__ als,
                                            float* __restrict__ ald, int N) {
  int node = blockIdx.x * 4 + (threadIdx.x >> 6);
  int lane = threadIdx.x & 63;
  if (node >= N) return;
  const f16x4* hp = (const f16x4*)(h + (size_t)node * 768 + lane * 12);
  float ss = 0.f, sd = 0.f;
  int cbase = lane * 12;
  #pragma unroll
  for (int q = 0; q < 3; q++) {
    f16x4 hv = hp[q];
    #pragma unroll
    for (int j = 0; j < 4; j++) {
      int c = cbase + q * 4 + j;
      float v = (float)hv[j];
      ss += v * a_src[c];
      sd += v * a_dst[c];
    }
  }
  const int red = (H == 8) ? 8 : 64;
  #pragma unroll
  for (int off = 1; off < red; off <<= 1) {
    ss += __shfl_xor(ss, off);
    sd += __shfl_xor(sd, off);
  }
  if (H == 8) {
    if ((lane & 7) == 0) {
      als[(size_t)node * 8 + (lane >> 3)] = ss;
      ald[(size_t)node * 8 + (lane >> 3)] = sd;
    }
  } else {
    if (lane == 0) { als[node] = ss; ald[node] = sd; }
  }
}

// ---------------- fused segment softmax + aggregation + bias (+ELU) ----------------
// proven 73.5us structure (rounds 4/6/11), unsplit, untouched.
template <int H, bool FINAL>
__global__ __launch_bounds__(192) void k_aggregate(
    const f16* __restrict__ h, const float* __restrict__ als,
    const float* __restrict__ ald, const int* __restrict__ starts,
    const int* __restrict__ src_sorted, const float* __restrict__ bias,
    void* __restrict__ outv, int nvalid) {
  const int n = blockIdx.x;
  const int t = threadIdx.x;
  if (n >= nvalid) return;
  __shared__ float s_ex[256 * H];
  __shared__ int s_src[256];
  __shared__ float s_zp[3][H];
  const int start = starts[n];
  const int deg = starts[n + 1] - start;
  const int lane = t & 63, wv = t >> 6;
  const int hA = (H == 8) ? (t & 7) : 0;
  const int myh = (H == 8) ? (t / 24) : 0;
  const float ald_A = ald[(size_t)n * H + hA];

  float zpart = 0.f;
  float4 acc = {0.f, 0.f, 0.f, 0.f};

  for (int cb = 0; cb < deg; cb += 256) {
    const int cnt = min(256, deg - cb);
    for (int idx = t; idx < cnt * H; idx += 192) {
      const int e = (H == 8) ? (idx >> 3) : idx;
      const int s = src_sorted[start + cb + e];
      if (H == 1 || (idx & 7) == 0) s_src[e] = s;
      float v = als[(size_t)s * H + hA] + ald_A;
      v = v > 0.f ? v : LRELU_SLOPE * v;
      const float ex = __expf(v);
      s_ex[idx] = ex;
      zpart += ex;
    }
    __syncthreads();
    for (int e = 0; e < cnt; e++) {
      const f16x4 hv = *(const f16x4*)(h + (size_t)s_src[e] * 768 + 4 * t);
      const float a = s_ex[e * H + myh];
      acc.x += a * (float)hv[0];
      acc.y += a * (float)hv[1];
      acc.z += a * (float)hv[2];
      acc.w += a * (float)hv[3];
    }
    __syncthreads();
  }

  if (H == 8) {
    #pragma unroll
    for (int off = 8; off < 64; off <<= 1) zpart += __shfl_xor(zpart, off);
    if (lane < 8) s_zp[wv][lane] = zpart;
  } else {
    #pragma unroll
    for (int off = 1; off < 64; off <<= 1) zpart += __shfl_xor(zpart, off);
    if (lane == 0) s_zp[wv][0] = zpart;
  }
  __syncthreads();
  const float z = s_zp[0][myh] + s_zp[1][myh] + s_zp[2][myh];
  const float inv = 1.f / (z + 1e-16f);

  const float4 bv = *(const float4*)(bias + 4 * t);
  float v0 = acc.x * inv + bv.x;
  float v1 = acc.y * inv + bv.y;
  float v2 = acc.z * inv + bv.z;
  float v3 = acc.w * inv + bv.w;
  if (!FINAL) {
    v0 = v0 > 0.f ? v0 : expm1f(v0);
    v1 = v1 > 0.f ? v1 : expm1f(v1);
    v2 = v2 > 0.f ? v2 : expm1f(v2);
    v3 = v3 > 0.f ? v3 : expm1f(v3);
    f16x4 o;
    o[0] = (f16)v0; o[1] = (f16)v1; o[2] = (f16)v2; o[3] = (f16)v3;
    *(f16x4*)((f16*)outv + (size_t)n * 768 + 4 * t) = o;
  } else {
    float4 o = {v0, v1, v2, v3};
    *(float4*)((float*)outv + (size_t)n * 768 + 4 * t) = o;
  }
}

// ---------------- launcher ----------------
extern "C" void kernel_launch(void* const* d_in, const int* in_sizes, int n_in,
                              void* d_out, int out_size, void* d_ws, size_t ws_size,
                              hipStream_t stream) {
  const float* x   = (const float*)d_in[0];
  const int*   ei  = (const int*)d_in[1];
  const float* W1  = (const float*)d_in[2];
  const float* as1 = (const float*)d_in[3];
  const float* ad1 = (const float*)d_in[4];
  const float* b1  = (const float*)d_in[5];
  const float* W2  = (const float*)d_in[6];
  const float* as2 = (const float*)d_in[7];
  const float* ad2 = (const float*)d_in[8];
  const float* b2  = (const float*)d_in[9];

  const int N = in_sizes[0] / 768;
  const int E = in_sizes[1] / 2;
  const int Mpad = (N + 127) & ~127;
  const int* srcp = ei;
  const int* dstp = ei + E;

  char* p = (char*)d_ws;
  auto alloc = [&](size_t b) { char* r = p; p += (b + 255) & ~(size_t)255; return r; };
  f16*   bufX   = (f16*)alloc((size_t)Mpad * 768 * sizeof(f16));  // x_h, then out1
  f16*   bufH   = (f16*)alloc((size_t)Mpad * 768 * sizeof(f16));  // h1, then h2
  f16*   Wt1    = (f16*)alloc((size_t)768 * 768 * sizeof(f16));
  f16*   Wt2    = (f16*)alloc((size_t)768 * 768 * sizeof(f16));
  float* als1   = (float*)alloc((size_t)N * 8 * sizeof(float));
  float* ald1   = (float*)alloc((size_t)N * 8 * sizeof(float));
  float* als2   = (float*)alloc((size_t)N * sizeof(float));
  float* ald2   = (float*)alloc((size_t)N * sizeof(float));
  int*   counts = (int*)alloc((size_t)N * sizeof(int));
  int*   starts = (int*)alloc(((size_t)N + 1) * sizeof(int));
  int*   cursor = (int*)alloc((size_t)N * sizeof(int));
  int*   srcs   = (int*)alloc((size_t)E * sizeof(int));

  // CSR build
  hipMemsetAsync(counts, 0, (size_t)N * sizeof(int), stream);
  k_hist<<<dim3(512), dim3(256), 0, stream>>>(dstp, E, counts);
  k_scan_block<<<dim3(1), dim3(1024), 0, stream>>>(counts, starts, cursor, N);
  k_fill<<<dim3(512), dim3(256), 0, stream>>>(srcp, dstp, E, cursor, srcs);

  // prep
  k_prep_xh<<<dim3(1024), dim3(256), 0, stream>>>(x, bufX, N, Mpad);
  k_transpose_w2<<<dim3(24, 24, 2), dim3(256), 0, stream>>>(W1, W2, Wt1, Wt2);

  const int nwg = (Mpad / 128) * 12;

  // layer 1
  k_gemm_f16<<<dim3(nwg), dim3(256), 0, stream>>>(bufX, Wt1, bufH, N);
  k_al<8><<<dim3((N + 3) / 4), dim3(256), 0, stream>>>(bufH, as1, ad1, als1, ald1, N);
  k_aggregate<8, false><<<dim3(N), dim3(192), 0, stream>>>(bufH, als1, ald1, starts, srcs, b1, bufX, N);

  // layer 2 (bufX pad rows still hold k_prep_xh zeros)
  k_gemm_f16<<<dim3(nwg), dim3(256), 0, stream>>>(bufX, Wt2, bufH, N);
  k_al<1><<<dim3((N + 3) / 4), dim3(256), 0, stream>>>(bufH, as2, ad2, als2, ald2, N);
  k_aggregate<1, true><<<dim3(N), dim3(192), 0, stream>>>(bufH, als2, ald2, starts, srcs, b2, d_out, N);
}

// Round 15
// 325.623 us; speedup vs baseline: 1.4603x; 1.4603x over previous
//
#include <hip/hip_runtime.h>
#include <cstdint>
#include <cstddef>

typedef _Float16 f16;
typedef _Float16 f16x4 __attribute__((ext_vector_type(4)));
typedef _Float16 f16x8 __attribute__((ext_vector_type(8)));
typedef float f32x4 __attribute__((ext_vector_type(4)));

#define LRELU_SLOPE 0.2f

#define GLL16(g, l)                                                          \
  __builtin_amdgcn_global_load_lds(                                          \
      (const __attribute__((address_space(1))) void*)(g),                    \
      (__attribute__((address_space(3))) void*)(l), 16, 0, 0)

// ---------------- prep: x (f32) -> x_h (f16), padded rows zeroed ----------------
__global__ __launch_bounds__(256) void k_prep_xh(const float* __restrict__ x,
                                                 f16* __restrict__ xh,
                                                 int nvalid, int npad) {
  int total = npad * 192;
  for (int idx = blockIdx.x * blockDim.x + threadIdx.x; idx < total;
       idx += gridDim.x * blockDim.x) {
    int row = idx / 192;
    f16x4 o;
    if (row < nvalid) {
      const float4 v = *(const float4*)(x + (size_t)idx * 4);
      o[0] = (f16)v.x; o[1] = (f16)v.y; o[2] = (f16)v.z; o[3] = (f16)v.w;
    } else {
      o[0] = (f16)0.f; o[1] = (f16)0.f; o[2] = (f16)0.f; o[3] = (f16)0.f;
    }
    *(f16x4*)(xh + (size_t)idx * 4) = o;
  }
}

// ---------------- both W [768][768] f32 -> Wt [n][k] f16, one launch ----------------
__global__ __launch_bounds__(256) void k_transpose_w2(const float* __restrict__ W1,
                                                      const float* __restrict__ W2,
                                                      f16* __restrict__ Wt1,
                                                      f16* __restrict__ Wt2) {
  const float* W = blockIdx.z ? W2 : W1;
  f16* Wt = blockIdx.z ? Wt2 : Wt1;
  __shared__ float tile[32][33];
  int bn = blockIdx.x * 32;
  int bk = blockIdx.y * 32;
  int tx = threadIdx.x & 31, ty = threadIdx.x >> 5;
  #pragma unroll
  for (int r = ty; r < 32; r += 8)
    tile[r][tx] = W[(size_t)(bk + r) * 768 + bn + tx];
  __syncthreads();
  #pragma unroll
  for (int r = ty; r < 32; r += 8)
    Wt[(size_t)(bn + r) * 768 + bk + tx] = (f16)tile[tx][r];
}

// ---------------- CSR build ----------------
__global__ void k_hist(const int* __restrict__ dst, int E, int* __restrict__ counts) {
  for (int e = blockIdx.x * blockDim.x + threadIdx.x; e < E;
       e += gridDim.x * blockDim.x) atomicAdd(&counts[dst[e]], 1);
}

__global__ __launch_bounds__(1024) void k_scan_block(const int* __restrict__ counts,
                                                     int* __restrict__ starts,
                                                     int* __restrict__ cursor, int n) {
  const int t = threadIdx.x;
  const int nthr = 1024;
  const int chunk = (n + nthr - 1) / nthr;
  const int base = t * chunk;
  int tsum = 0;
  for (int i = 0; i < chunk; i++) {
    int idx = base + i;
    if (idx < n) tsum += counts[idx];
  }
  int lane = t & 63, wv = t >> 6;
  int s = tsum;
  #pragma unroll
  for (int off = 1; off < 64; off <<= 1) {
    int tmp = __shfl_up(s, off);
    if (lane >= off) s += tmp;
  }
  __shared__ int wsum[16];
  if (lane == 63) wsum[wv] = s;
  __syncthreads();
  int woff = 0;
  for (int w = 0; w < wv; w++) woff += wsum[w];
  int run = woff + s - tsum;
  for (int i = 0; i < chunk; i++) {
    int idx = base + i;
    if (idx < n) {
      starts[idx] = run;
      cursor[idx] = run;
      run += counts[idx];
    }
  }
  if (t == nthr - 1) starts[n] = run;
}

__global__ void k_fill(const int* __restrict__ src, const int* __restrict__ dst, int E,
                       int* __restrict__ cursor, int* __restrict__ src_sorted) {
  for (int e = blockIdx.x * blockDim.x + threadIdx.x; e < E;
       e += gridDim.x * blockDim.x) {
    int slot = atomicAdd(&cursor[dst[e]], 1);
    src_sorted[slot] = src[e];
  }
}

// ---------------- fp16 MFMA GEMM: BK=64, double-buffered global_load_lds --------
// T3-lite 2-phase (proven round 11): STAGE(next) issued BEFORE compute, raw
// s_barrier + LATE vmcnt(0) per step. Bijective chunked XCD swizzle (m204),
// m-major: all 6 bn of an m-tile on one XCD -> A-panel fetched once, L2-reused 6x.
__global__ __launch_bounds__(256) void k_gemm_f16(const f16* __restrict__ A,
                                                  const f16* __restrict__ Bt,
                                                  f16* __restrict__ C, int Mvalid) {
  __shared__ __align__(16) f16 As[2][8192];  // [buf][128*64]
  __shared__ __align__(16) f16 Bs[2][8192];
  const int K = 768;
  const int tid = threadIdx.x;

  // bijective XCD swizzle: xcd = orig%8 gets a contiguous wgid chunk (m204)
  const int nwg = gridDim.x;
  const int orig = blockIdx.x;
  const int q = nwg >> 3, r = nwg & 7;
  const int xcd = orig & 7;
  const int wgid = (xcd < r ? xcd * (q + 1) : r * (q + 1) + (xcd - r) * q) + (orig >> 3);
  const int bm = (wgid / 6) * 128;
  const int bn = (wgid - (wgid / 6) * 6) * 128;

  const int lane = tid & 63;
  const int wave = tid >> 6;
  const int wr = (wave >> 1) * 64;
  const int wc = (wave & 1) * 64;

  // staging: pass p, cell = p*256+tid; row = cell>>3; logical chunk = (cell&7)^(row&7)
  size_t goffA[4], goffB[4];
  #pragma unroll
  for (int p = 0; p < 4; p++) {
    const int cell = p * 256 + tid;
    const int row = cell >> 3;
    const int cl = (cell & 7) ^ (row & 7);
    goffA[p] = (size_t)(bm + row) * K + cl * 8;
    goffB[p] = (size_t)(bn + row) * K + cl * 8;
  }

  f32x4 acc[4][4];
  const f32x4 vzero = {0.f, 0.f, 0.f, 0.f};
  #pragma unroll
  for (int i = 0; i < 4; i++)
    #pragma unroll
    for (int j = 0; j < 4; j++) acc[i][j] = vzero;

  const int fr = lane & 15;
  const int fq = lane >> 4;

  #define STAGE(buf, k0)                                                      \
    do {                                                                      \
      _Pragma("unroll")                                                       \
      for (int p = 0; p < 4; p++) {                                           \
        GLL16(A + goffA[p] + (k0), &As[buf][p * 2048 + wave * 512]);          \
        GLL16(Bt + goffB[p] + (k0), &Bs[buf][p * 2048 + wave * 512]);         \
      }                                                                       \
    } while (0)

  // prologue
  STAGE(0, 0);
  asm volatile("s_waitcnt vmcnt(0)" ::: "memory");
  __builtin_amdgcn_s_barrier();

  const int NT = K / 64;  // 12
  int cur = 0;
  for (int t = 0; t < NT; t++) {
    if (t + 1 < NT) STAGE(cur ^ 1, (t + 1) * 64);
    // compute tile t from buf cur (compiler inserts lgkmcnt for ds_read->MFMA)
    #pragma unroll
    for (int ks = 0; ks < 2; ks++) {
      f16x8 af[4], bf[4];
      #pragma unroll
      for (int i = 0; i < 4; i++) {
        const int rr = wr + i * 16 + fr;
        const int phys = (ks * 4 + fq) ^ (rr & 7);
        af[i] = *(const f16x8*)(&As[cur][rr * 64 + phys * 8]);
      }
      #pragma unroll
      for (int j = 0; j < 4; j++) {
        const int rr = wc + j * 16 + fr;
        const int phys = (ks * 4 + fq) ^ (rr & 7);
        bf[j] = *(const f16x8*)(&Bs[cur][rr * 64 + phys * 8]);
      }
      #pragma unroll
      for (int i = 0; i < 4; i++)
        #pragma unroll
        for (int j = 0; j < 4; j++)
          acc[i][j] = __builtin_amdgcn_mfma_f32_16x16x32_f16(af[i], bf[j], acc[i][j], 0, 0, 0);
    }
    // late drain: next tile's loads had the whole compute phase to land
    asm volatile("s_waitcnt vmcnt(0)" ::: "memory");
    __builtin_amdgcn_s_barrier();
    cur ^= 1;
  }
  #undef STAGE

  #pragma unroll
  for (int i = 0; i < 4; i++) {
    #pragma unroll
    for (int j = 0; j < 4; j++) {
      const int col = bn + wc + j * 16 + fr;
      #pragma unroll
      for (int rg = 0; rg < 4; rg++) {
        const int row = bm + wr + i * 16 + fq * 4 + rg;
        if (row < Mvalid) C[(size_t)row * 768 + col] = (f16)acc[i][j][rg];
      }
    }
  }
}

// ---------------- attention logits: al[n][h] = sum_c h[n][h*C+c]*a[h][c] ----------
template <int H>
__global__ __launch_bounds__(256) void k_al(const f16* __restrict__ h,
                                            const float* __restrict__ a_src,
                                            const float* __restrict__ a_dst,
                                            float* __restrict__ als,
                                            float* __restrict__ ald, int N) {
  int node = blockIdx.x * 4 + (threadIdx.x >> 6);
  int lane = threadIdx.x & 63;
  if (node >= N) return;
  const f16x4* hp = (const f16x4*)(h + (size_t)node * 768 + lane * 12);
  float ss = 0.f, sd = 0.f;
  int cbase = lane * 12;
  #pragma unroll
  for (int q = 0; q < 3; q++) {
    f16x4 hv = hp[q];
    #pragma unroll
    for (int j = 0; j < 4; j++) {
      int c = cbase + q * 4 + j;
      float v = (float)hv[j];
      ss += v * a_src[c];
      sd += v * a_dst[c];
    }
  }
  const int red = (H == 8) ? 8 : 64;
  #pragma unroll
  for (int off = 1; off < red; off <<= 1) {
    ss += __shfl_xor(ss, off);
    sd += __shfl_xor(sd, off);
  }
  if (H == 8) {
    if ((lane & 7) == 0) {
      als[(size_t)node * 8 + (lane >> 3)] = ss;
      ald[(size_t)node * 8 + (lane >> 3)] = sd;
    }
  } else {
    if (lane == 0) { als[node] = ss; ald[node] = sd; }
  }
}

// ---------------- fused segment softmax + aggregation + bias (+ELU) ----------------
// proven 73.5us structure; nbase allows half-grid dispatch for profile visibility.
template <int H, bool FINAL>
__global__ __launch_bounds__(192) void k_aggregate(
    const f16* __restrict__ h, const float* __restrict__ als,
    const float* __restrict__ ald, const int* __restrict__ starts,
    const int* __restrict__ src_sorted, const float* __restrict__ bias,
    void* __restrict__ outv, int nvalid, int nbase) {
  const int n = nbase + blockIdx.x;
  const int t = threadIdx.x;
  if (n >= nvalid) return;
  __shared__ float s_ex[256 * H];
  __shared__ int s_src[256];
  __shared__ float s_zp[3][H];
  const int start = starts[n];
  const int deg = starts[n + 1] - start;
  const int lane = t & 63, wv = t >> 6;
  const int hA = (H == 8) ? (t & 7) : 0;
  const int myh = (H == 8) ? (t / 24) : 0;
  const float ald_A = ald[(size_t)n * H + hA];

  float zpart = 0.f;
  float4 acc = {0.f, 0.f, 0.f, 0.f};

  for (int cb = 0; cb < deg; cb += 256) {
    const int cnt = min(256, deg - cb);
    for (int idx = t; idx < cnt * H; idx += 192) {
      const int e = (H == 8) ? (idx >> 3) : idx;
      const int s = src_sorted[start + cb + e];
      if (H == 1 || (idx & 7) == 0) s_src[e] = s;
      float v = als[(size_t)s * H + hA] + ald_A;
      v = v > 0.f ? v : LRELU_SLOPE * v;
      const float ex = __expf(v);
      s_ex[idx] = ex;
      zpart += ex;
    }
    __syncthreads();
    for (int e = 0; e < cnt; e++) {
      const f16x4 hv = *(const f16x4*)(h + (size_t)s_src[e] * 768 + 4 * t);
      const float a = s_ex[e * H + myh];
      acc.x += a * (float)hv[0];
      acc.y += a * (float)hv[1];
      acc.z += a * (float)hv[2];
      acc.w += a * (float)hv[3];
    }
    __syncthreads();
  }

  if (H == 8) {
    #pragma unroll
    for (int off = 8; off < 64; off <<= 1) zpart += __shfl_xor(zpart, off);
    if (lane < 8) s_zp[wv][lane] = zpart;
  } else {
    #pragma unroll
    for (int off = 1; off < 64; off <<= 1) zpart += __shfl_xor(zpart, off);
    if (lane == 0) s_zp[wv][0] = zpart;
  }
  __syncthreads();
  const float z = s_zp[0][myh] + s_zp[1][myh] + s_zp[2][myh];
  const float inv = 1.f / (z + 1e-16f);

  const float4 bv = *(const float4*)(bias + 4 * t);
  float v0 = acc.x * inv + bv.x;
  float v1 = acc.y * inv + bv.y;
  float v2 = acc.z * inv + bv.z;
  float v3 = acc.w * inv + bv.w;
  if (!FINAL) {
    v0 = v0 > 0.f ? v0 : expm1f(v0);
    v1 = v1 > 0.f ? v1 : expm1f(v1);
    v2 = v2 > 0.f ? v2 : expm1f(v2);
    v3 = v3 > 0.f ? v3 : expm1f(v3);
    f16x4 o;
    o[0] = (f16)v0; o[1] = (f16)v1; o[2] = (f16)v2; o[3] = (f16)v3;
    *(f16x4*)((f16*)outv + (size_t)n * 768 + 4 * t) = o;
  } else {
    float4 o = {v0, v1, v2, v3};
    *(float4*)((float*)outv + (size_t)n * 768 + 4 * t) = o;
  }
}

// ---------------- launcher ----------------
extern "C" void kernel_launch(void* const* d_in, const int* in_sizes, int n_in,
                              void* d_out, int out_size, void* d_ws, size_t ws_size,
                              hipStream_t stream) {
  const float* x   = (const float*)d_in[0];
  const int*   ei  = (const int*)d_in[1];
  const float* W1  = (const float*)d_in[2];
  const float* as1 = (const float*)d_in[3];
  const float* ad1 = (const float*)d_in[4];
  const float* b1  = (const float*)d_in[5];
  const float* W2  = (const float*)d_in[6];
  const float* as2 = (const float*)d_in[7];
  const float* ad2 = (const float*)d_in[8];
  const float* b2  = (const float*)d_in[9];

  const int N = in_sizes[0] / 768;
  const int E = in_sizes[1] / 2;
  const int Mpad = (N + 127) & ~127;
  const int* srcp = ei;
  const int* dstp = ei + E;

  char* p = (char*)d_ws;
  auto alloc = [&](size_t b) { char* r = p; p += (b + 255) & ~(size_t)255; return r; };
  f16*   bufX   = (f16*)alloc((size_t)Mpad * 768 * sizeof(f16));  // x_h, then out1
  f16*   bufH   = (f16*)alloc((size_t)Mpad * 768 * sizeof(f16));  // h1, then h2
  f16*   Wt1    = (f16*)alloc((size_t)768 * 768 * sizeof(f16));
  f16*   Wt2    = (f16*)alloc((size_t)768 * 768 * sizeof(f16));
  float* als1   = (float*)alloc((size_t)N * 8 * sizeof(float));
  float* ald1   = (float*)alloc((size_t)N * 8 * sizeof(float));
  float* als2   = (float*)alloc((size_t)N * sizeof(float));
  float* ald2   = (float*)alloc((size_t)N * sizeof(float));
  int*   counts = (int*)alloc((size_t)N * sizeof(int));
  int*   starts = (int*)alloc(((size_t)N + 1) * sizeof(int));
  int*   cursor = (int*)alloc((size_t)N * sizeof(int));
  int*   srcs   = (int*)alloc((size_t)E * sizeof(int));

  // CSR build
  hipMemsetAsync(counts, 0, (size_t)N * sizeof(int), stream);
  k_hist<<<dim3(512), dim3(256), 0, stream>>>(dstp, E, counts);
  k_scan_block<<<dim3(1), dim3(1024), 0, stream>>>(counts, starts, cursor, N);
  k_fill<<<dim3(512), dim3(256), 0, stream>>>(srcp, dstp, E, cursor, srcs);

  // prep
  k_prep_xh<<<dim3(1024), dim3(256), 0, stream>>>(x, bufX, N, Mpad);
  k_transpose_w2<<<dim3(24, 24, 2), dim3(256), 0, stream>>>(W1, W2, Wt1, Wt2);

  const int nwg = (Mpad / 128) * 6;
  const int nh1 = (N + 1) / 2;
  const int nh2 = N - nh1;

  // layer 1 (aggregate split in two for profile visibility)
  k_gemm_f16<<<dim3(nwg), dim3(256), 0, stream>>>(bufX, Wt1, bufH, N);
  k_al<8><<<dim3((N + 3) / 4), dim3(256), 0, stream>>>(bufH, as1, ad1, als1, ald1, N);
  k_aggregate<8, false><<<dim3(nh1), dim3(192), 0, stream>>>(
      bufH, als1, ald1, starts, srcs, b1, bufX, N, 0);
  k_aggregate<8, false><<<dim3(nh2), dim3(192), 0, stream>>>(
      bufH, als1, ald1, starts, srcs, b1, bufX, N, nh1);

  // layer 2
  k_gemm_f16<<<dim3(nwg), dim3(256), 0, stream>>>(bufX, Wt2, bufH, N);
  k_al<1><<<dim3((N + 3) / 4), dim3(256), 0, stream>>>(bufH, as2, ad2, als2, ald2, N);
  k_aggregate<1, true><<<dim3(N), dim3(192), 0, stream>>>(
      bufH, als2, ald2, starts, srcs, b2, d_out, N, 0);
}